// Round 11
// baseline (80.704 us; speedup 1.0000x reference)
//
#include <hip/hip_runtime.h>

#define BB 4
#define NN 4096
#define TPB 1024             // 16 waves
#define IBL 32               // i's per block (16 lane-slots x IPT=2)
#define STREAMS 64           // 16 waves x 4 quarter-waves
#define JPS (NN / STREAMS)   // 64 j's per stream
#define GRP 4                // LDS prefetch depth

#if __has_builtin(__builtin_amdgcn_sqrtf)
  #define FAST_SQRT __builtin_amdgcn_sqrtf
#else
  #define FAST_SQRT sqrtf
#endif

__device__ __forceinline__ float clip1(float x) {
    return fminf(fmaxf(x, -1.0f), 1.0f);   // -> v_med3_f32
}

// ONE dispatch, no workspace. Same skeleton as R9 (512 blocks = 2/CU,
// 32 waves/CU, 64 KB LDS stage of batch b, 64 quarter-wave j-streams).
// Change vs R9: ONE combined branch per j instead of two — halves the
// v_cmp->s_cbranch stall count; taken path handles both i's (relu zeroes
// whichever i missed). Early-out exact: radii in [0,1] -> target <= 2,
// d2 >= 4 -> penalty == 0. Diagonal: dx = xi - xj = 0 -> clip(0) = 0.
__global__ __launch_bounds__(TPB, 8) void ncp_one(
    const float* __restrict__ coords,   // [BB,NN,3]
    const float* __restrict__ radii,    // [BB,NN]
    float* __restrict__ out)
{
    __shared__ __align__(16) char smem[65536];
    float4* pts = (float4*)smem;        // [NN] phases 0/1
    float*  red = (float*)smem;         // [STREAMS][IBL][3] phase 2 (24 KB)

    const int b = blockIdx.z;
    const int ibase = blockIdx.x * IBL;

    for (int p = threadIdx.x; p < NN; p += TPB) {
        const int g = b * NN + p;
        pts[p] = make_float4(coords[3 * g + 0], coords[3 * g + 1],
                             coords[3 * g + 2], radii[g]);
    }
    __syncthreads();

    const int l = threadIdx.x & 63;
    const int li = l & 15;
    const int q  = l >> 4;              // quarter-wave 0..3
    const int w  = threadIdx.x >> 6;    // wave 0..15
    const int stream = w * 4 + q;       // 0..63
    const int jbase = stream * JPS;

    const float4 me0 = pts[ibase + li];
    const float4 me1 = pts[ibase + 16 + li];
    const float m2x0 = -2.0f * me0.x, m2y0 = -2.0f * me0.y, m2z0 = -2.0f * me0.z;
    const float m2x1 = -2.0f * me1.x, m2y1 = -2.0f * me1.y, m2z1 = -2.0f * me1.z;
    const float n20 = fmaf(me0.z, me0.z, fmaf(me0.y, me0.y, me0.x * me0.x));
    const float n21 = fmaf(me1.z, me1.z, fmaf(me1.y, me1.y, me1.x * me1.x));
    const float thr0 = 4.0f - n20;
    const float thr1 = 4.0f - n21;

    float ax0 = 0.0f, ay0 = 0.0f, az0 = 0.0f;
    float ax1 = 0.0f, ay1 = 0.0f, az1 = 0.0f;

    for (int k0 = 0; k0 < JPS; k0 += GRP) {
        float4 c[GRP];
        #pragma unroll
        for (int g = 0; g < GRP; ++g)
            c[g] = pts[jbase + k0 + g];     // quarter-wave-uniform LDS read
        #pragma unroll
        for (int g = 0; g < GRP; ++g) {
            const float nj = fmaf(c[g].z, c[g].z,
                             fmaf(c[g].y, c[g].y, c[g].x * c[g].x));
            const float sd0 = fmaf(m2z0, c[g].z,
                              fmaf(m2y0, c[g].y, fmaf(m2x0, c[g].x, nj)));
            const float sd1 = fmaf(m2z1, c[g].z,
                              fmaf(m2y1, c[g].y, fmaf(m2x1, c[g].x, nj)));
            // ONE branch per j covering both i's (128 pairs)
            if (__builtin_expect(__any((sd0 < thr0) | (sd1 < thr1)), 0)) {
                const float d0   = FAST_SQRT(fmaxf(sd0 + n20, 0.0f));
                const float d1   = FAST_SQRT(fmaxf(sd1 + n21, 0.0f));
                const float p0   = fmaxf(fmaxf(1.0f, me0.w + c[g].w) - d0, 0.0f);
                const float p1   = fmaxf(fmaxf(1.0f, me1.w + c[g].w) - d1, 0.0f);
                const float dx0  = me0.x - c[g].x;   // exact; diagonal -> 0
                const float dy0  = me0.y - c[g].y;
                const float dz0  = me0.z - c[g].z;
                const float dx1  = me1.x - c[g].x;
                const float dy1  = me1.y - c[g].y;
                const float dz1  = me1.z - c[g].z;
                ax0 = fmaf(p0, clip1(dx0), ax0);
                ay0 = fmaf(p0, clip1(dy0), ay0);
                az0 = fmaf(p0, clip1(dz0), az0);
                ax1 = fmaf(p1, clip1(dx1), ax1);
                ay1 = fmaf(p1, clip1(dy1), ay1);
                az1 = fmaf(p1, clip1(dz1), az1);
            }
        }
    }

    __syncthreads();                    // all pts reads done before LDS reuse
    {
        const int r0 = (stream * IBL + li) * 3;
        const int r1 = (stream * IBL + 16 + li) * 3;
        red[r0 + 0] = ax0; red[r0 + 1] = ay0; red[r0 + 2] = az0;
        red[r1 + 0] = ax1; red[r1 + 1] = ay1; red[r1 + 2] = az1;
    }
    __syncthreads();

    if (threadIdx.x < IBL * 3) {        // 96 outputs per block
        float acc = 0.0f;
        #pragma unroll
        for (int s = 0; s < STREAMS; ++s)   // ascending s == ascending j
            acc += red[s * (IBL * 3) + threadIdx.x];
        const int o = (b * NN + ibase) * 3 + threadIdx.x;
        out[o] = fmaf(0.1f / (float)NN, acc, coords[o]);
    }
}

extern "C" void kernel_launch(void* const* d_in, const int* in_sizes, int n_in,
                              void* d_out, int out_size, void* d_ws, size_t ws_size,
                              hipStream_t stream) {
    const float* coords = (const float*)d_in[0];
    const float* radii  = (const float*)d_in[1];
    float* out = (float*)d_out;
    (void)d_ws; (void)ws_size;

    ncp_one<<<dim3(NN / IBL, 1, BB), TPB, 0, stream>>>(coords, radii, out);
}

// Round 12
// 73.236 us; speedup vs baseline: 1.1020x; 1.1020x over previous
//
#include <hip/hip_runtime.h>

#define BB 4
#define NN 4096
#define TPB 1024             // 16 waves
#define IBL 32               // i's per block (16 lane-slots x IPT=2)
#define STREAMS 64           // 16 waves x 4 quarter-waves
#define JPS (NN / STREAMS)   // 64 j's per stream
#define GRP 4                // LDS prefetch depth

#if __has_builtin(__builtin_amdgcn_sqrtf)
  #define FAST_SQRT __builtin_amdgcn_sqrtf
#else
  #define FAST_SQRT sqrtf
#endif

__device__ __forceinline__ float clip1(float x) {
    return fminf(fmaxf(x, -1.0f), 1.0f);   // -> v_med3_f32
}

// ONE dispatch, no workspace. R9 skeleton (best: 73.4 us): 512 blocks =
// 2/CU, 32 waves/CU, 64 quarter-wave j-streams, per-i branches (R10's
// merged branch regressed: union take-rate 54% vs 32%, 1.7x taken work).
// Change vs R9: LDS float4 = (x, y, z, ||p||^2) -- nj precomputed at stage
// time, cutting 3 fma from the miss path (13 -> 10 instrs). Radii live in a
// separate LDS array read ONLY in the taken path (~32% of iters).
// Early-out exact: radii in [0,1] -> target <= 2; d2 >= 4 -> penalty == 0.
// Diagonal: dx = xi - xj = 0 exactly -> clip(0) = 0 (matches reference).
__global__ __launch_bounds__(TPB, 8) void ncp_one(
    const float* __restrict__ coords,   // [BB,NN,3]
    const float* __restrict__ radii,    // [BB,NN]
    float* __restrict__ out)
{
    __shared__ __align__(16) char smem[81920];   // 64 KB pts4 + 16 KB rad
    float4* pts = (float4*)smem;        // [NN] (x,y,z,n2) phases 0/1
    float*  rad = (float*)(smem + 65536);   // [NN]
    float*  red = (float*)smem;         // [STREAMS][IBL][3] phase 2 (24 KB)

    const int b = blockIdx.z;
    const int ibase = blockIdx.x * IBL;

    for (int p = threadIdx.x; p < NN; p += TPB) {
        const int g = b * NN + p;
        const float x = coords[3 * g + 0];
        const float y = coords[3 * g + 1];
        const float z = coords[3 * g + 2];
        pts[p] = make_float4(x, y, z, fmaf(z, z, fmaf(y, y, x * x)));
        rad[p] = radii[g];
    }
    __syncthreads();

    const int l = threadIdx.x & 63;
    const int li = l & 15;
    const int q  = l >> 4;              // quarter-wave 0..3
    const int w  = threadIdx.x >> 6;    // wave 0..15
    const int stream = w * 4 + q;       // 0..63
    const int jbase = stream * JPS;

    const float4 me0 = pts[ibase + li];
    const float4 me1 = pts[ibase + 16 + li];
    const float ri0 = rad[ibase + li];
    const float ri1 = rad[ibase + 16 + li];
    const float m2x0 = -2.0f * me0.x, m2y0 = -2.0f * me0.y, m2z0 = -2.0f * me0.z;
    const float m2x1 = -2.0f * me1.x, m2y1 = -2.0f * me1.y, m2z1 = -2.0f * me1.z;
    const float n20 = me0.w, n21 = me1.w;
    const float thr0 = 4.0f - n20;
    const float thr1 = 4.0f - n21;

    float ax0 = 0.0f, ay0 = 0.0f, az0 = 0.0f;
    float ax1 = 0.0f, ay1 = 0.0f, az1 = 0.0f;

    for (int k0 = 0; k0 < JPS; k0 += GRP) {
        float4 c[GRP];
        #pragma unroll
        for (int g = 0; g < GRP; ++g)
            c[g] = pts[jbase + k0 + g];     // quarter-wave-uniform LDS read
        #pragma unroll
        for (int g = 0; g < GRP; ++g) {
            // c[g].w == nj (precomputed): miss path = 6 fma + 2 cmp + 2 br
            const float sd0 = fmaf(m2z0, c[g].z,
                              fmaf(m2y0, c[g].y, fmaf(m2x0, c[g].x, c[g].w)));
            const float sd1 = fmaf(m2z1, c[g].z,
                              fmaf(m2y1, c[g].y, fmaf(m2x1, c[g].x, c[g].w)));
            if (__any(sd0 < thr0)) {
                const float rj   = rad[jbase + k0 + g];   // taken-path only
                const float dist = FAST_SQRT(fmaxf(sd0 + n20, 0.0f));
                const float tgt  = fmaxf(1.0f, ri0 + rj);
                const float p    = fmaxf(tgt - dist, 0.0f);
                const float dx   = me0.x - c[g].x;   // exact; diag -> 0
                const float dy   = me0.y - c[g].y;
                const float dz   = me0.z - c[g].z;
                ax0 = fmaf(p, clip1(dx), ax0);
                ay0 = fmaf(p, clip1(dy), ay0);
                az0 = fmaf(p, clip1(dz), az0);
            }
            if (__any(sd1 < thr1)) {
                const float rj   = rad[jbase + k0 + g];
                const float dist = FAST_SQRT(fmaxf(sd1 + n21, 0.0f));
                const float tgt  = fmaxf(1.0f, ri1 + rj);
                const float p    = fmaxf(tgt - dist, 0.0f);
                const float dx   = me1.x - c[g].x;
                const float dy   = me1.y - c[g].y;
                const float dz   = me1.z - c[g].z;
                ax1 = fmaf(p, clip1(dx), ax1);
                ay1 = fmaf(p, clip1(dy), ay1);
                az1 = fmaf(p, clip1(dz), az1);
            }
        }
    }

    __syncthreads();                    // all pts reads done before LDS reuse
    {
        const int r0 = (stream * IBL + li) * 3;
        const int r1 = (stream * IBL + 16 + li) * 3;
        red[r0 + 0] = ax0; red[r0 + 1] = ay0; red[r0 + 2] = az0;
        red[r1 + 0] = ax1; red[r1 + 1] = ay1; red[r1 + 2] = az1;
    }
    __syncthreads();

    if (threadIdx.x < IBL * 3) {        // 96 outputs per block
        float acc = 0.0f;
        #pragma unroll
        for (int s = 0; s < STREAMS; ++s)   // ascending s == ascending j
            acc += red[s * (IBL * 3) + threadIdx.x];
        const int o = (b * NN + ibase) * 3 + threadIdx.x;
        out[o] = fmaf(0.1f / (float)NN, acc, coords[o]);
    }
}

extern "C" void kernel_launch(void* const* d_in, const int* in_sizes, int n_in,
                              void* d_out, int out_size, void* d_ws, size_t ws_size,
                              hipStream_t stream) {
    const float* coords = (const float*)d_in[0];
    const float* radii  = (const float*)d_in[1];
    float* out = (float*)d_out;
    (void)d_ws; (void)ws_size;

    ncp_one<<<dim3(NN / IBL, 1, BB), TPB, 0, stream>>>(coords, radii, out);
}

// Round 13
// 69.691 us; speedup vs baseline: 1.1580x; 1.0509x over previous
//
#include <hip/hip_runtime.h>

#define BB 4
#define NN 4096
#define TPB 1024             // 16 waves
#define IBL 32               // i's per block (16 lane-slots x IPT=2)
#define STREAMS 64           // 16 waves x 4 quarter-waves
#define JPS (NN / STREAMS)   // 64 j's per stream
#define GRP 4                // LDS prefetch depth

#if __has_builtin(__builtin_amdgcn_sqrtf)
  #define FAST_SQRT __builtin_amdgcn_sqrtf
#else
  #define FAST_SQRT sqrtf
#endif

__device__ __forceinline__ float clip1(float x) {
    return fminf(fmaxf(x, -1.0f), 1.0f);   // -> v_med3_f32
}

// ONE dispatch, no workspace. R11 skeleton (best: 73.2 us): 512 blocks =
// 2/CU, 32 waves/CU, 64 quarter-wave j-streams, LDS float4 = (x,y,z,||p||^2),
// radii in separate LDS (taken-path only), per-i branches.
// Change vs R11: TIGHTENED early-out. target = max(1, ri+rj) <= 1 + ri
// (radii in [0,1)), so d2 >= (1+ri)^2 -> penalty == 0 exactly. thr becomes
// (1+ri)^2 - n2i — still a per-i constant, zero extra miss-path work, but
// per-__any take-rate drops 32% -> ~16.5% (halves the ~10us taken-path cost
// sized by R10's merged-branch regression).
// Diagonal: dx = xi - xj = 0 exactly -> clip(0) = 0 (matches reference).
__global__ __launch_bounds__(TPB, 8) void ncp_one(
    const float* __restrict__ coords,   // [BB,NN,3]
    const float* __restrict__ radii,    // [BB,NN]
    float* __restrict__ out)
{
    __shared__ __align__(16) char smem[81920];   // 64 KB pts4 + 16 KB rad
    float4* pts = (float4*)smem;        // [NN] (x,y,z,n2) phases 0/1
    float*  rad = (float*)(smem + 65536);   // [NN]
    float*  red = (float*)smem;         // [STREAMS][IBL][3] phase 2 (24 KB)

    const int b = blockIdx.z;
    const int ibase = blockIdx.x * IBL;

    for (int p = threadIdx.x; p < NN; p += TPB) {
        const int g = b * NN + p;
        const float x = coords[3 * g + 0];
        const float y = coords[3 * g + 1];
        const float z = coords[3 * g + 2];
        pts[p] = make_float4(x, y, z, fmaf(z, z, fmaf(y, y, x * x)));
        rad[p] = radii[g];
    }
    __syncthreads();

    const int l = threadIdx.x & 63;
    const int li = l & 15;
    const int q  = l >> 4;              // quarter-wave 0..3
    const int w  = threadIdx.x >> 6;    // wave 0..15
    const int stream = w * 4 + q;       // 0..63
    const int jbase = stream * JPS;

    const float4 me0 = pts[ibase + li];
    const float4 me1 = pts[ibase + 16 + li];
    const float ri0 = rad[ibase + li];
    const float ri1 = rad[ibase + 16 + li];
    const float m2x0 = -2.0f * me0.x, m2y0 = -2.0f * me0.y, m2z0 = -2.0f * me0.z;
    const float m2x1 = -2.0f * me1.x, m2y1 = -2.0f * me1.y, m2z1 = -2.0f * me1.z;
    const float n20 = me0.w, n21 = me1.w;
    // Tight bound: target <= 1 + ri  =>  skip when d2 >= (1+ri)^2
    const float thr0 = (1.0f + ri0) * (1.0f + ri0) - n20;
    const float thr1 = (1.0f + ri1) * (1.0f + ri1) - n21;

    float ax0 = 0.0f, ay0 = 0.0f, az0 = 0.0f;
    float ax1 = 0.0f, ay1 = 0.0f, az1 = 0.0f;

    for (int k0 = 0; k0 < JPS; k0 += GRP) {
        float4 c[GRP];
        #pragma unroll
        for (int g = 0; g < GRP; ++g)
            c[g] = pts[jbase + k0 + g];     // quarter-wave-uniform LDS read
        #pragma unroll
        for (int g = 0; g < GRP; ++g) {
            // c[g].w == nj (precomputed): miss path = 6 fma + 2 cmp + 2 br
            const float sd0 = fmaf(m2z0, c[g].z,
                              fmaf(m2y0, c[g].y, fmaf(m2x0, c[g].x, c[g].w)));
            const float sd1 = fmaf(m2z1, c[g].z,
                              fmaf(m2y1, c[g].y, fmaf(m2x1, c[g].x, c[g].w)));
            if (__any(sd0 < thr0)) {
                const float rj   = rad[jbase + k0 + g];   // taken-path only
                const float dist = FAST_SQRT(fmaxf(sd0 + n20, 0.0f));
                const float tgt  = fmaxf(1.0f, ri0 + rj);
                const float p    = fmaxf(tgt - dist, 0.0f);
                const float dx   = me0.x - c[g].x;   // exact; diag -> 0
                const float dy   = me0.y - c[g].y;
                const float dz   = me0.z - c[g].z;
                ax0 = fmaf(p, clip1(dx), ax0);
                ay0 = fmaf(p, clip1(dy), ay0);
                az0 = fmaf(p, clip1(dz), az0);
            }
            if (__any(sd1 < thr1)) {
                const float rj   = rad[jbase + k0 + g];
                const float dist = FAST_SQRT(fmaxf(sd1 + n21, 0.0f));
                const float tgt  = fmaxf(1.0f, ri1 + rj);
                const float p    = fmaxf(tgt - dist, 0.0f);
                const float dx   = me1.x - c[g].x;
                const float dy   = me1.y - c[g].y;
                const float dz   = me1.z - c[g].z;
                ax1 = fmaf(p, clip1(dx), ax1);
                ay1 = fmaf(p, clip1(dy), ay1);
                az1 = fmaf(p, clip1(dz), az1);
            }
        }
    }

    __syncthreads();                    // all pts reads done before LDS reuse
    {
        const int r0 = (stream * IBL + li) * 3;
        const int r1 = (stream * IBL + 16 + li) * 3;
        red[r0 + 0] = ax0; red[r0 + 1] = ay0; red[r0 + 2] = az0;
        red[r1 + 0] = ax1; red[r1 + 1] = ay1; red[r1 + 2] = az1;
    }
    __syncthreads();

    if (threadIdx.x < IBL * 3) {        // 96 outputs per block
        float acc = 0.0f;
        #pragma unroll
        for (int s = 0; s < STREAMS; ++s)   // ascending s == ascending j
            acc += red[s * (IBL * 3) + threadIdx.x];
        const int o = (b * NN + ibase) * 3 + threadIdx.x;
        out[o] = fmaf(0.1f / (float)NN, acc, coords[o]);
    }
}

extern "C" void kernel_launch(void* const* d_in, const int* in_sizes, int n_in,
                              void* d_out, int out_size, void* d_ws, size_t ws_size,
                              hipStream_t stream) {
    const float* coords = (const float*)d_in[0];
    const float* radii  = (const float*)d_in[1];
    float* out = (float*)d_out;
    (void)d_ws; (void)ws_size;

    ncp_one<<<dim3(NN / IBL, 1, BB), TPB, 0, stream>>>(coords, radii, out);
}